// Round 9
// baseline (63550.006 us; speedup 1.0000x reference)
//
#include <hip/hip_runtime.h>
#include <cstdint>

#define T_LEN 16384
#define X_DIM 256
#define H_DIM 1024
#define NREP  8                    // h-buffer replicas (slice spreading)
#define SLOT_U32 1024              // col c lives at dword c (linear, proven r2)
#define REP_U32  (2 * SLOT_U32)    // ping-pong slots per replica
#define FLAG_OFF (NREP * REP_U32)  // 16384 dwords = 64 KB

typedef unsigned int u32;
typedef unsigned long long u64;
typedef u32   u32x4 __attribute__((ext_vector_type(4)));
typedef float f32x4 __attribute__((ext_vector_type(4)));

// ---------------------------------------------------------------------------
// Device-scope coherent ops. sc0 sc1 -> MALL is the coherence point (per-XCD
// L2s are NOT cross-coherent; r3: sc0-only visibility is eviction-timing-
// dependent). Every published dword self-validates via a 2-bit step tag in
// its mantissa LSBs -> only 4 B atomicity required.
// Poll history: r2 serial poll w/ dropout = proven 22.25ms. r4/r5: in-flight
// regs crossing asm boundaries = hazard. r6: scalar streams, no dropout =
// fabric collapse. r7: no dropout + s_sleep(4) = sampling quantized >=256cy.
// r8: asm-tie forced scratch spill (VGPR 52, +2.75ms). r9 poll combines the
// surviving pieces: ONE asm block + twin-buffer sampling + EXEC DROPOUT +
// no sleep + sentinel accept + C++ full recheck + r2 fallback.
// ---------------------------------------------------------------------------
__device__ __forceinline__ void coh_store4(u32* p, u32x4 v) {
  asm volatile("global_store_dwordx4 %0, %1, off sc0 sc1" :: "v"(p), "v"(v) : "memory");
}
__device__ __forceinline__ void coh_store1(u32* p, u32 v) {
  asm volatile("global_store_dword %0, %1, off sc0 sc1" :: "v"(p), "v"(v) : "memory");
}
__device__ __forceinline__ u32 coh_load1(const u32* p) {
  u32 v;
  asm volatile("global_load_dword %0, %1, off sc0 sc1\n\ts_waitcnt vmcnt(0)"
               : "=v"(v) : "v"(p) : "memory");
  return v;
}
// r2-proven poll iteration (fallback path): 4 dwordx4 + vmcnt(0).
__device__ __forceinline__ void poll_group(const u32* p, u32x4& a, u32x4& b,
                                           u32x4& c, u32x4& d) {
  asm volatile(
      "global_load_dwordx4 %0, %4, off sc0 sc1\n\t"
      "global_load_dwordx4 %1, %4, off offset:16 sc0 sc1\n\t"
      "global_load_dwordx4 %2, %4, off offset:32 sc0 sc1\n\t"
      "global_load_dwordx4 %3, %4, off offset:48 sc0 sc1\n\t"
      "s_waitcnt vmcnt(0)"
      : "=&v"(a), "=&v"(b), "=&v"(c), "=&v"(d) : "v"(p) : "memory");
}

__device__ __forceinline__ u32 tagchk(const u32x4& a, const u32x4& b,
                                      const u32x4& c, const u32x4& d, u32 tag) {
  const u32 m = (a.x ^ tag) | (a.y ^ tag) | (a.z ^ tag) | (a.w ^ tag)
              | (b.x ^ tag) | (b.y ^ tag) | (b.z ^ tag) | (b.w ^ tag)
              | (c.x ^ tag) | (c.y ^ tag) | (c.z ^ tag) | (c.w ^ tag)
              | (d.x ^ tag) | (d.y ^ tag) | (d.z ^ tag) | (d.w ^ tag);
  return m & 3u;
}

__device__ __forceinline__ float fast_tanh(float x) {
  x = fminf(9.0f, fmaxf(-9.0f, x));
  const float e = __builtin_amdgcn_exp2f(x * 2.8853900817779268f); // 2*log2(e)
  return (e - 1.0f) * __builtin_amdgcn_rcpf(e + 1.0f);
}

// 64-lane all-reduce: 4x DPP row_ror (within-16) + shfl_xor 16,32 [r2-proven].
template <int CTRL>
__device__ __forceinline__ float ror_add(float x) {
  const int y = __builtin_amdgcn_update_dpp(0, __float_as_int(x), CTRL, 0xF, 0xF, false);
  return x + __int_as_float(y);
}
__device__ __forceinline__ float redux64(float x) {
  x = ror_add<0x121>(x);
  x = ror_add<0x122>(x);
  x = ror_add<0x124>(x);
  x = ror_add<0x128>(x);
  x += __shfl_xor(x, 16, 64);
  x += __shfl_xor(x, 32, 64);
  return x;
}

// One sample batch: 4 sentinel dwords (in-asm checkable) + 4 data dwordx4.
#define ISSUE_SET(s0, s1, s2, s3, f0, f1, f2, f3)                        \
  "global_load_dword %[" #s0 "], %[gp], off sc0 sc1\n\t"                 \
  "global_load_dword %[" #s1 "], %[gp], off offset:16 sc0 sc1\n\t"       \
  "global_load_dword %[" #s2 "], %[gp], off offset:32 sc0 sc1\n\t"       \
  "global_load_dword %[" #s3 "], %[gp], off offset:48 sc0 sc1\n\t"       \
  "global_load_dwordx4 %[" #f0 "], %[gp], off sc0 sc1\n\t"               \
  "global_load_dwordx4 %[" #f1 "], %[gp], off offset:16 sc0 sc1\n\t"     \
  "global_load_dwordx4 %[" #f2 "], %[gp], off offset:32 sc0 sc1\n\t"     \
  "global_load_dwordx4 %[" #f3 "], %[gp], off offset:48 sc0 sc1\n\t"

#define CHK_SENT(s0, s1, s2, s3)                                         \
  "v_xor_b32 %[t], %[stag], %[" #s0 "]\n\t"                              \
  "v_xor_b32 %[u], %[stag], %[" #s1 "]\n\t"                              \
  "v_or_b32 %[t], %[t], %[u]\n\t"                                        \
  "v_xor_b32 %[u], %[stag], %[" #s2 "]\n\t"                              \
  "v_or_b32 %[t], %[t], %[u]\n\t"                                        \
  "v_xor_b32 %[u], %[stag], %[" #s3 "]\n\t"                              \
  "v_or_b32 %[t], %[t], %[u]\n\t"                                        \
  "v_and_b32 %[t], 3, %[t]\n\t"                                          \
  "v_cmp_ne_u32 vcc, 0, %[t]\n\t"   /* vcc = per-lane MISMATCH */

// ---------------------------------------------------------------------------
// Kernel 0: seed slot 0 of every replica with h0 (tag 0) and zero the filler
// done-flag. Poison 0xAAAAAAAA has tag LSBs 0b10, never matching slot0 tags
// {0,2} (overwritten here) nor slot1's first expected tag 1.
// ---------------------------------------------------------------------------
__global__ void hinit(const float* __restrict__ h0, u32* __restrict__ ws) {
  const int i = threadIdx.x;              // 256 threads x 4 cols
  const f32x4 h = *(const f32x4*)(h0 + i * 4);
  u32x4 v;
  v.x = __float_as_uint(h[0]) & ~3u;
  v.y = __float_as_uint(h[1]) & ~3u;
  v.z = __float_as_uint(h[2]) & ~3u;
  v.w = __float_as_uint(h[3]) & ~3u;
  const int idx = i * 4;                  // linear layout, 16 B aligned
#pragma unroll
  for (int rep = 0; rep < NREP; ++rep)
    coh_store4(ws + (size_t)rep * REP_U32 + idx, v);
  if (i < 2) coh_store1(ws + FLAG_OFF + i, 0u);  // done flag + spare
}

// ---------------------------------------------------------------------------
// Kernel 1: Bx_c = x @ B^T + c into d_out. Unchanged (proven).
// ---------------------------------------------------------------------------
__global__ __launch_bounds__(256) void gemm_bx(const float* __restrict__ x,
                                               const float* __restrict__ Bm,
                                               const float* __restrict__ c,
                                               float* __restrict__ out) {
  __shared__ float xs[64][68];
  __shared__ float bs[64][68];

  const int tid = threadIdx.x;
  const int t0  = blockIdx.x * 64;
  const int h0  = blockIdx.y * 64;
  const int lr  = tid >> 4;
  const int lc  = tid & 15;

  float acc[4][4] = {};

  for (int kb = 0; kb < X_DIM; kb += 64) {
    const int kk  = (tid & 15) * 4;
    const int tt0 = tid >> 4;
#pragma unroll
    for (int i = 0; i < 4; ++i) {
      const int tt = tt0 + i * 16;
      const f32x4 xv = *(const f32x4*)(x  + (size_t)(t0 + tt) * X_DIM + kb + kk);
      const f32x4 bv = *(const f32x4*)(Bm + (size_t)(h0 + tt) * X_DIM + kb + kk);
#pragma unroll
      for (int q = 0; q < 4; ++q) {
        xs[kk + q][tt] = xv[q];
        bs[kk + q][tt] = bv[q];
      }
    }
    __syncthreads();

#pragma unroll 8
    for (int k = 0; k < 64; ++k) {
      const f32x4 xv = *(const f32x4*)&xs[k][lr * 4];
      const f32x4 bv = *(const f32x4*)&bs[k][lc * 4];
#pragma unroll
      for (int i = 0; i < 4; ++i)
#pragma unroll
        for (int j = 0; j < 4; ++j)
          acc[i][j] = fmaf(xv[i], bv[j], acc[i][j]);
    }
    __syncthreads();
  }

  const f32x4 cv = *(const f32x4*)(c + h0 + lc * 4);
#pragma unroll
  for (int i = 0; i < 4; ++i) {
    f32x4 o;
#pragma unroll
    for (int j = 0; j < 4; ++j) o[j] = acc[i][j] + cv[j];
    *(f32x4*)(out + (size_t)(t0 + lr * 4 + i) * H_DIM + h0 + lc * 4) = o;
  }
}

// ---------------------------------------------------------------------------
// Kernel 2: 256 blocks. Blocks 0-63 = scan workers, EXACT r2 structure
// (4 waves/block, wave owns 4 rows, lane l consumes h[16l..16l+15]; publish
// lanes<32; redux64; 2-deep bx prefetch) with ONE change: the poll.
//
// Twin-buffer dropout poll (one asm block): two batches in flight, each =
// 4 sentinels + 4 dwordx4. vmcnt(8) retires the older batch (FIFO).
// Sentinel-satisfied lanes RETIRE via `s_and_b64 exec, exec, vcc` -> their
// landed registers freeze (no later exec-masked issue touches a retired
// lane), wh records which set. Exit on execz or SGPR deadman (2^21 half-
// rounds, <=~300ms bound). After vmcnt(0)+exec restore, C++ selects wh?B:A
// (landed regs - safe per r7), FULL 16-tag recheck, and falls back to the
// r2-proven serial poll on any mismatch. Sampling period ~RT/2 vs r2's ~RT;
// dropout keeps steady-state fabric traffic at laggards-only.
// Skew proof unchanged: publishing t+1 requires full h(t) validated (all 64
// groups, one per lane) -> every wave finished t-1. Entry/exit vmcnt(0)
// preserves the per-step drain ordering same-dword publishes across reuse.
// Blocks 64-255 = DVFS fillers (unchanged, hard-capped).
// ---------------------------------------------------------------------------
__global__ __launch_bounds__(256) void rnn_scan(const float* __restrict__ A_raw,
                                                float* __restrict__ out,
                                                u32* __restrict__ ws) {
  const int tid = threadIdx.x;

  if (blockIdx.x >= 64) {
    // ---- filler: keep the DPM governor at high clock ----
    const u32* flag = ws + FLAG_OFF;
    float f0 = 0.f, f1 = 0.f, f2 = 0.f, f3 = 0.f;
    float f4 = 0.f, f5 = 0.f, f6 = 0.f, f7 = 0.f;
    const float m = 1.0000001f, ad = 1e-9f;
    for (int outer = 0; outer < 32768; ++outer) {   // hard cap ~56 ms @2.4GHz
      if (coh_load1(flag) != 0u) break;
      for (int i = 0; i < 256; ++i) {               // ~4096 cyc of VALU burn
        f0 = fmaf(f0, m, ad); f1 = fmaf(f1, m, ad);
        f2 = fmaf(f2, m, ad); f3 = fmaf(f3, m, ad);
        f4 = fmaf(f4, m, ad); f5 = fmaf(f5, m, ad);
        f6 = fmaf(f6, m, ad); f7 = fmaf(f7, m, ad);
      }
    }
    if (f0 + f1 + f2 + f3 + f4 + f5 + f6 + f7 == 123456.789f && tid == 0)
      coh_store1(ws + FLAG_OFF + 1, 1u);            // DCE guard, never true
    return;
  }

  // ---- worker wave (r2 geometry) ----
  const int lane    = tid & 63;
  const int wv      = tid >> 6;
  const int wg      = blockIdx.x;
  const int gw      = wg * 4 + wv;      // global wave id 0..255
  const int rowbase = gw * 4;
  const int r       = lane & 3;
  const int row     = rowbase + r;      // this lane's output row (lanes mod 4)

  // A fragment: a[rr][k] = 0.1*A_raw[rowbase+rr][16*lane+k] + 0.9*(col==row).
  // (No asm-tie, no launch_bounds games -- r8 proved those spill to scratch.)
  float a[4][16];
#pragma unroll
  for (int rr = 0; rr < 4; ++rr) {
#pragma unroll
    for (int k4 = 0; k4 < 4; ++k4) {
      const f32x4 v = *(const f32x4*)(A_raw + (size_t)(rowbase + rr) * H_DIM +
                                      lane * 16 + k4 * 4);
#pragma unroll
      for (int q = 0; q < 4; ++q) {
        const int col = lane * 16 + k4 * 4 + q;
        a[rr][k4 * 4 + q] = 0.1f * v[q] + (col == rowbase + rr ? 0.9f : 0.0f);
      }
    }
  }

  u32* hbuf = ws;
  const u32* ppoll0 = hbuf + (size_t)(gw & (NREP - 1)) * REP_U32 + 16 * lane;
  u32* pub = hbuf + (size_t)(lane >> 2) * REP_U32 + rowbase + r;  // lanes<32

  // 2-deep bx prefetch: out[t] rows are only overwritten by THIS wave at
  // step t -> reading out[t+2] at step t is read-before-write, same wave.
  float bx_val = out[(size_t)0 * H_DIM + row];
  float bx_n1  = out[(size_t)1 * H_DIM + row];

  int  dead2   = 1 << 20;   // fallback-loop budget (r2-proven envelope)
  bool timeout = false;

  for (int t = 0; t < T_LEN; ++t) {
    const u32 tag = (u32)(t & 3);
    const u32* p  = ppoll0 + (t & 1) * SLOT_U32;

    u32x4 fa0, fa1, fa2, fa3, fb0, fb1, fb2, fb3;
    u32 sa0, sa1, sa2, sa3, sb0, sb1, sb2, sb3;
    u32 tmp1, tmp2, wh, tmo, sdead;
    u64 sv, sm, st;
    asm volatile(
        "s_waitcnt vmcnt(0)\n\t"            // entry drain (per-step invariant)
        "s_mov_b64 %[sv], exec\n\t"
        "s_mov_b32 %[sd], 0x200000\n\t"     // deadman: 2^21 half-rounds
        "v_mov_b32 %[wh], 0\n\t"
        "v_mov_b32 %[to], 0\n\t"
        ISSUE_SET(xa0, xa1, xa2, xa3, qa0, qa1, qa2, qa3)   // batch A (8 VMEM)
        ISSUE_SET(xb0, xb1, xb2, xb3, qb0, qb1, qb2, qb3)   // batch B (8 VMEM)
        "Lp%=:\n\t"
        "s_waitcnt vmcnt(8)\n\t"            // older batch (A) fully landed
        CHK_SENT(xa0, xa1, xa2, xa3)        // vcc = per-lane mismatch
        "s_and_b64 exec, exec, vcc\n\t"     // retire satisfied-A (wh stays 0)
        "s_cbranch_execz Ld%=\n\t"
        "s_sub_u32 %[sd], %[sd], 1\n\t"
        "s_cbranch_scc1 Lt%=\n\t"
        ISSUE_SET(xa0, xa1, xa2, xa3, qa0, qa1, qa2, qa3)   // reissue (actives)
        "s_waitcnt vmcnt(8)\n\t"            // batch B landed
        CHK_SENT(xb0, xb1, xb2, xb3)
        "s_andn2_b64 %[sm], exec, vcc\n\t"  // satisfied-B lanes
        "s_mov_b64 %[st], exec\n\t"
        "s_mov_b64 exec, %[sm]\n\t"
        "v_mov_b32 %[wh], 1\n\t"            // mark accepted-from-B
        "s_mov_b64 exec, %[st]\n\t"
        "s_and_b64 exec, exec, vcc\n\t"     // retire satisfied-B
        "s_cbranch_execz Ld%=\n\t"
        "s_sub_u32 %[sd], %[sd], 1\n\t"
        "s_cbranch_scc1 Lt%=\n\t"
        ISSUE_SET(xb0, xb1, xb2, xb3, qb0, qb1, qb2, qb3)
        "s_branch Lp%=\n\t"
        "Lt%=:\n\t"
        "v_mov_b32 %[to], 1\n\t"            // stuck lanes only
        "Ld%=:\n\t"
        "s_waitcnt vmcnt(0)\n\t"            // everything landed before exit
        "s_mov_b64 exec, %[sv]\n\t"
        : [qa0]"=&v"(fa0), [qa1]"=&v"(fa1), [qa2]"=&v"(fa2), [qa3]"=&v"(fa3),
          [qb0]"=&v"(fb0), [qb1]"=&v"(fb1), [qb2]"=&v"(fb2), [qb3]"=&v"(fb3),
          [xa0]"=&v"(sa0), [xa1]"=&v"(sa1), [xa2]"=&v"(sa2), [xa3]"=&v"(sa3),
          [xb0]"=&v"(sb0), [xb1]"=&v"(sb1), [xb2]"=&v"(sb2), [xb3]"=&v"(sb3),
          [t]"=&v"(tmp1), [u]"=&v"(tmp2), [wh]"=&v"(wh), [to]"=&v"(tmo),
          [sd]"=&s"(sdead), [sv]"=&s"(sv), [sm]"=&s"(sm), [st]"=&s"(st)
        : [gp]"v"(p), [stag]"s"(tag)
        : "vcc", "scc", "memory");

    if (__any(tmo != 0u)) {
      if (lane == 0) coh_store1(ws + FLAG_OFF, 1u);  // fail fast, release fillers
      return;
    }

    // Select accepted batch (all regs landed -> safe to select in C++; r7).
    u32x4 hA = wh ? fb0 : fa0;
    u32x4 hB = wh ? fb1 : fa1;
    u32x4 hC = wh ? fb2 : fa2;
    u32x4 hD = wh ? fb3 : fa3;

    // Full-tag recheck; r2-proven serial-poll fallback on any mismatch
    // (sentinel pass does not imply all 16 data dwords were visible).
    if (__any(tagchk(hA, hB, hC, hD, tag) != 0u)) {
      for (;;) {
        poll_group(p, hA, hB, hC, hD);
        if (tagchk(hA, hB, hC, hD, tag) == 0u) break;
        if (--dead2 == 0) { timeout = true; break; }
      }
      if (__any(timeout)) {
        if (lane == 0) coh_store1(ws + FLAG_OFF, 1u);
        return;
      }
    }

    // Issue bx(t+2) now; ~2 full step periods to cover HBM latency.
    const int tn2 = (t + 2 < T_LEN) ? t + 2 : t;
    const float bx_n2 = out[(size_t)tn2 * H_DIM + row];

    // Partial dots straight from poll registers (tag bits left in mantissa,
    // rel err <= 2^-22 -- same as proven version).
    const f32x4 f0 = __builtin_bit_cast(f32x4, hA);
    const f32x4 f1 = __builtin_bit_cast(f32x4, hB);
    const f32x4 f2 = __builtin_bit_cast(f32x4, hC);
    const f32x4 f3 = __builtin_bit_cast(f32x4, hD);
    float ac0 = 0.f, ac1 = 0.f, ac2 = 0.f, ac3 = 0.f;
#pragma unroll
    for (int j = 0; j < 4; ++j) {
      ac0 = fmaf(a[0][j], f0[j], ac0); ac1 = fmaf(a[1][j], f0[j], ac1);
      ac2 = fmaf(a[2][j], f0[j], ac2); ac3 = fmaf(a[3][j], f0[j], ac3);
    }
#pragma unroll
    for (int j = 0; j < 4; ++j) {
      ac0 = fmaf(a[0][4 + j], f1[j], ac0); ac1 = fmaf(a[1][4 + j], f1[j], ac1);
      ac2 = fmaf(a[2][4 + j], f1[j], ac2); ac3 = fmaf(a[3][4 + j], f1[j], ac3);
    }
#pragma unroll
    for (int j = 0; j < 4; ++j) {
      ac0 = fmaf(a[0][8 + j], f2[j], ac0); ac1 = fmaf(a[1][8 + j], f2[j], ac1);
      ac2 = fmaf(a[2][8 + j], f2[j], ac2); ac3 = fmaf(a[3][8 + j], f2[j], ac3);
    }
#pragma unroll
    for (int j = 0; j < 4; ++j) {
      ac0 = fmaf(a[0][12 + j], f3[j], ac0); ac1 = fmaf(a[1][12 + j], f3[j], ac1);
      ac2 = fmaf(a[2][12 + j], f3[j], ac2); ac3 = fmaf(a[3][12 + j], f3[j], ac3);
    }

    // 64-lane all-reduce of the 4 row sums [r2-proven].
    ac0 = redux64(ac0);
    ac1 = redux64(ac1);
    ac2 = redux64(ac2);
    ac3 = redux64(ac3);

    float accr = ac0;
    if (r == 1) accr = ac1;
    if (r == 2) accr = ac2;
    if (r == 3) accr = ac3;
    const float v = fast_tanh(accr + bx_val);
    bx_val = bx_n1;
    bx_n1  = bx_n2;

    const u32 nt = (u32)((t + 1) & 3);
    if (lane < 4 * NREP) {
      // lanes 0..31: publish to replica lane>>2, row-class lane&3.
      coh_store1(pub + (size_t)((t + 1) & 1) * SLOT_U32,
                 (__float_as_uint(v) & ~3u) | nt);
    } else if (lane < 4 * NREP + 4) {
      // lanes 32..35: clean output write (bx already consumed this step).
      out[(size_t)t * H_DIM + row] = v;
    }
  }

  if (gw == 0 && lane == 0) coh_store1(ws + FLAG_OFF, 1u);  // release fillers
}

// ---------------------------------------------------------------------------
extern "C" void kernel_launch(void* const* d_in, const int* in_sizes, int n_in,
                              void* d_out, int out_size, void* d_ws, size_t ws_size,
                              hipStream_t stream) {
  const float* x    = (const float*)d_in[0];  // (T, X)
  const float* h0   = (const float*)d_in[1];  // (H,)
  const float* Araw = (const float*)d_in[2];  // (H, H)
  const float* B    = (const float*)d_in[3];  // (H, X)
  const float* c    = (const float*)d_in[4];  // (H,)
  float* out = (float*)d_out;                 // (T, H)
  u32* ws    = (u32*)d_ws;                    // 64 KB hbuf + flag dwords

  hinit<<<1, 256, 0, stream>>>(h0, ws);
  dim3 g(T_LEN / 64, H_DIM / 64);
  gemm_bx<<<g, 256, 0, stream>>>(x, B, c, out);
  rnn_scan<<<256, 256, 0, stream>>>(Araw, out, ws);
}

// Round 10
// 35883.508 us; speedup vs baseline: 1.7710x; 1.7710x over previous
//
#include <hip/hip_runtime.h>
#include <cstdint>

#define T_LEN 16384
#define X_DIM 256
#define H_DIM 1024
#define NREP  8                    // h-buffer replicas (slice spreading)
#define SLOT_U32 1024              // col c lives at dword c (linear, proven r2)
#define REP_U32  (2 * SLOT_U32)    // ping-pong slots per replica
#define FLAG_OFF (NREP * REP_U32)  // 16384 dwords = 64 KB
#define ATR_OFF_U32 32768          // Atrans at byte 128K (clear of proven 80K)
#define WS_NEED ((size_t)ATR_OFF_U32 * 4 + (size_t)H_DIM * H_DIM * 4)

typedef unsigned int u32;
typedef u32   u32x4 __attribute__((ext_vector_type(4)));
typedef float f32x4 __attribute__((ext_vector_type(4)));

// ---------------------------------------------------------------------------
// Device-scope coherent ops. sc0 sc1 -> MALL is the coherence point (per-XCD
// L2s are NOT cross-coherent; r3: sc0-only visibility is eviction-timing-
// dependent). Every published dword self-validates via a 2-bit step tag in
// its mantissa LSBs -> only 4 B atomicity required.
// POLL DOCTRINE (r4-r9 concluded, 5 variants, 5 losses): the serial
// 4x dwordx4 + vmcnt(0) + exec-dropout poll is at the fabric optimum.
// Every added outstanding request (rings r4/r5, scalar streams r6, sentinel
// duplication r7, twin-buffer r9) costs more in MALL queueing than it buys
// in sampling rate. PERMANENTLY CLOSED -- do not restructure the poll.
// ---------------------------------------------------------------------------
__device__ __forceinline__ void coh_store4(u32* p, u32x4 v) {
  asm volatile("global_store_dwordx4 %0, %1, off sc0 sc1" :: "v"(p), "v"(v) : "memory");
}
__device__ __forceinline__ void coh_store1(u32* p, u32 v) {
  asm volatile("global_store_dword %0, %1, off sc0 sc1" :: "v"(p), "v"(v) : "memory");
}
__device__ __forceinline__ u32 coh_load1(const u32* p) {
  u32 v;
  asm volatile("global_load_dword %0, %1, off sc0 sc1\n\ts_waitcnt vmcnt(0)"
               : "=v"(v) : "v"(p) : "memory");
  return v;
}
// r2-proven poll iteration: 4 dwordx4 + vmcnt(0); values landed at asm exit.
__device__ __forceinline__ void poll_group(const u32* p, u32x4& a, u32x4& b,
                                           u32x4& c, u32x4& d) {
  asm volatile(
      "global_load_dwordx4 %0, %4, off sc0 sc1\n\t"
      "global_load_dwordx4 %1, %4, off offset:16 sc0 sc1\n\t"
      "global_load_dwordx4 %2, %4, off offset:32 sc0 sc1\n\t"
      "global_load_dwordx4 %3, %4, off offset:48 sc0 sc1\n\t"
      "s_waitcnt vmcnt(0)"
      : "=&v"(a), "=&v"(b), "=&v"(c), "=&v"(d) : "v"(p) : "memory");
}

__device__ __forceinline__ float fast_tanh(float x) {
  x = fminf(9.0f, fmaxf(-9.0f, x));
  const float e = __builtin_amdgcn_exp2f(x * 2.8853900817779268f); // 2*log2(e)
  return (e - 1.0f) * __builtin_amdgcn_rcpf(e + 1.0f);
}

// xor1 / xor2 within each quad via DPP quad_perm (pure VALU). [r6-r8 HW-proven]
__device__ __forceinline__ float dpp_xor1(float x) {  // quad_perm [1,0,3,2]
  return __int_as_float(__builtin_amdgcn_update_dpp(0, __float_as_int(x),
                                                    0xB1, 0xF, 0xF, false));
}
__device__ __forceinline__ float dpp_xor2(float x) {  // quad_perm [2,3,0,1]
  return __int_as_float(__builtin_amdgcn_update_dpp(0, __float_as_int(x),
                                                    0x4E, 0xF, 0xF, false));
}

// ---------------------------------------------------------------------------
// Kernel 0: seed slot 0 of every replica with h0 (tag 0) and zero the filler
// done-flag. Poison 0xAAAAAAAA has tag LSBs 0b10, never matching slot0 tags
// {0,2} (overwritten here) nor slot1's first expected tag 1.
// ---------------------------------------------------------------------------
__global__ void hinit(const float* __restrict__ h0, u32* __restrict__ ws) {
  const int i = threadIdx.x;              // 256 threads x 4 cols
  const f32x4 h = *(const f32x4*)(h0 + i * 4);
  u32x4 v;
  v.x = __float_as_uint(h[0]) & ~3u;
  v.y = __float_as_uint(h[1]) & ~3u;
  v.z = __float_as_uint(h[2]) & ~3u;
  v.w = __float_as_uint(h[3]) & ~3u;
  const int idx = i * 4;                  // linear layout, 16 B aligned
#pragma unroll
  for (int rep = 0; rep < NREP; ++rep)
    coh_store4(ws + (size_t)rep * REP_U32 + idx, v);
  if (i < 2) coh_store1(ws + FLAG_OFF + i, 0u);  // done flag + spare
}

// ---------------------------------------------------------------------------
// Kernel 0b (only if ws_size permits): Atrans = 0.1*A_raw + 0.9*I, laid out
// per-wave-fragment so the scan's 16 remat loads are contiguous/coalesced:
// slab (gw,rr,k4) = 64 lanes x 16 B = 1 KB; lane l's f32x4 at slab + 16*l.
// Removes ~130 VALU transform instrs/step from the scan's critical path
// (r2's VGPR=60 proves A cannot be register-resident; r8 proved forcing
// residency spills -- so make the remat CHEAP instead).
// ---------------------------------------------------------------------------
__global__ __launch_bounds__(256) void aprep(const float* __restrict__ A_raw,
                                             float* __restrict__ atr) {
  const int gw   = blockIdx.x;          // 0..255 (wave id)
  const int lane = threadIdx.x & 63;
  const int rr   = threadIdx.x >> 6;    // 0..3
  const int row  = gw * 4 + rr;
#pragma unroll
  for (int k4 = 0; k4 < 4; ++k4) {
    const f32x4 v = *(const f32x4*)(A_raw + (size_t)row * H_DIM +
                                    lane * 16 + k4 * 4);
    f32x4 o;
#pragma unroll
    for (int q = 0; q < 4; ++q) {
      const int col = lane * 16 + k4 * 4 + q;
      o[q] = 0.1f * v[q] + (col == row ? 0.9f : 0.0f);
    }
    *(f32x4*)(atr + ((size_t)((gw * 4 + rr) * 4 + k4) * 64 + lane) * 4) = o;
  }
}

// ---------------------------------------------------------------------------
// Kernel 1: Bx_c = x @ B^T + c into d_out. Unchanged (proven).
// ---------------------------------------------------------------------------
__global__ __launch_bounds__(256) void gemm_bx(const float* __restrict__ x,
                                               const float* __restrict__ Bm,
                                               const float* __restrict__ c,
                                               float* __restrict__ out) {
  __shared__ float xs[64][68];
  __shared__ float bs[64][68];

  const int tid = threadIdx.x;
  const int t0  = blockIdx.x * 64;
  const int h0  = blockIdx.y * 64;
  const int lr  = tid >> 4;
  const int lc  = tid & 15;

  float acc[4][4] = {};

  for (int kb = 0; kb < X_DIM; kb += 64) {
    const int kk  = (tid & 15) * 4;
    const int tt0 = tid >> 4;
#pragma unroll
    for (int i = 0; i < 4; ++i) {
      const int tt = tt0 + i * 16;
      const f32x4 xv = *(const f32x4*)(x  + (size_t)(t0 + tt) * X_DIM + kb + kk);
      const f32x4 bv = *(const f32x4*)(Bm + (size_t)(h0 + tt) * X_DIM + kb + kk);
#pragma unroll
      for (int q = 0; q < 4; ++q) {
        xs[kk + q][tt] = xv[q];
        bs[kk + q][tt] = bv[q];
      }
    }
    __syncthreads();

#pragma unroll 8
    for (int k = 0; k < 64; ++k) {
      const f32x4 xv = *(const f32x4*)&xs[k][lr * 4];
      const f32x4 bv = *(const f32x4*)&bs[k][lc * 4];
#pragma unroll
      for (int i = 0; i < 4; ++i)
#pragma unroll
        for (int j = 0; j < 4; ++j)
          acc[i][j] = fmaf(xv[i], bv[j], acc[i][j]);
    }
    __syncthreads();
  }

  const f32x4 cv = *(const f32x4*)(c + h0 + lc * 4);
#pragma unroll
  for (int i = 0; i < 4; ++i) {
    f32x4 o;
#pragma unroll
    for (int j = 0; j < 4; ++j) o[j] = acc[i][j] + cv[j];
    *(f32x4*)(out + (size_t)(t0 + lr * 4 + i) * H_DIM + h0 + lc * 4) = o;
  }
}

// ---------------------------------------------------------------------------
// Kernel 2: 256 blocks. Blocks 0-63 = scan workers -- EXACT r2 structure
// (4 waves/block, wave owns 4 rows, lane l polls h[16l..16l+15] from its
// replica with the r2 serial dropout poll; publish lanes<32; 2-deep bx
// prefetch) with two compute-side changes, both off the exchange path:
//  (1) FAST=true: A-fragment loads come from precomputed Atrans (no 0.1/0.9
//      transform per step; coalesced per-wave slabs, L2-resident 512KB/XCD).
//      FAST=false: exact r2 inline transform (ws too small fallback).
//  (2) transposed reduce [r6-r8 HW-proven]: 2 DPP quad_perm + 6 selects +
//      4 shfl replaces 16 DPP + 8 shfl + selects; lane ends holding its own
//      row's full dot product.
// Skew proof unchanged: publishing t+1 requires full h(t) validated (all 64
// groups, one per lane) -> every wave finished t-1 -> the (slot,tag) being
// overwritten has no remaining readers. Per-iteration vmcnt(0) in poll_group
// orders same-dword publishes across the 8-step (slot,tag) reuse period.
// Blocks 64-255 = DVFS fillers (unchanged, hard-capped).
// ---------------------------------------------------------------------------
template <bool FAST>
__global__ __launch_bounds__(256) void rnn_scan(const float* __restrict__ A_raw,
                                                float* __restrict__ out,
                                                u32* __restrict__ ws) {
  const int tid = threadIdx.x;

  if (blockIdx.x >= 64) {
    // ---- filler: keep the DPM governor at high clock ----
    const u32* flag = ws + FLAG_OFF;
    float f0 = 0.f, f1 = 0.f, f2 = 0.f, f3 = 0.f;
    float f4 = 0.f, f5 = 0.f, f6 = 0.f, f7 = 0.f;
    const float m = 1.0000001f, ad = 1e-9f;
    for (int outer = 0; outer < 32768; ++outer) {   // hard cap ~56 ms @2.4GHz
      if (coh_load1(flag) != 0u) break;
      for (int i = 0; i < 256; ++i) {               // ~4096 cyc of VALU burn
        f0 = fmaf(f0, m, ad); f1 = fmaf(f1, m, ad);
        f2 = fmaf(f2, m, ad); f3 = fmaf(f3, m, ad);
        f4 = fmaf(f4, m, ad); f5 = fmaf(f5, m, ad);
        f6 = fmaf(f6, m, ad); f7 = fmaf(f7, m, ad);
      }
    }
    if (f0 + f1 + f2 + f3 + f4 + f5 + f6 + f7 == 123456.789f && tid == 0)
      coh_store1(ws + FLAG_OFF + 1, 1u);            // DCE guard, never true
    return;
  }

  // ---- worker wave (r2 geometry) ----
  const int lane    = tid & 63;
  const int wv      = tid >> 6;
  const int wg      = blockIdx.x;
  const int gw      = wg * 4 + wv;      // global wave id 0..255
  const int rowbase = gw * 4;
  const int r       = lane & 3;
  const int row     = rowbase + r;      // this lane's output row (lanes mod 4)

  // Slow path keeps r2's A-fragment (inline transform, remat'd per step by
  // the compiler -- proven 22.25ms behavior). Fast path reads Atrans slabs.
  float a[4][16];
  const float* ab = (const float*)(ws + ATR_OFF_U32) + (size_t)gw * 4096 + lane * 4;
  if constexpr (!FAST) {
#pragma unroll
    for (int rr = 0; rr < 4; ++rr) {
#pragma unroll
      for (int k4 = 0; k4 < 4; ++k4) {
        const f32x4 v = *(const f32x4*)(A_raw + (size_t)(rowbase + rr) * H_DIM +
                                        lane * 16 + k4 * 4);
#pragma unroll
        for (int q = 0; q < 4; ++q) {
          const int col = lane * 16 + k4 * 4 + q;
          a[rr][k4 * 4 + q] = 0.1f * v[q] + (col == rowbase + rr ? 0.9f : 0.0f);
        }
      }
    }
  }

  u32* hbuf = ws;
  const u32* ppoll0 = hbuf + (size_t)(gw & (NREP - 1)) * REP_U32 + 16 * lane;
  u32* pub = hbuf + (size_t)(lane >> 2) * REP_U32 + rowbase + r;  // lanes<32

  // 2-deep bx prefetch: out[t] rows are only overwritten by THIS wave at
  // step t -> reading out[t+2] at step t is read-before-write, same wave.
  float bx_val = out[(size_t)0 * H_DIM + row];
  float bx_n1  = out[(size_t)1 * H_DIM + row];

  int  dead    = 1 << 20;   // total poll budget (r2-proven envelope)
  bool timeout = false;

  for (int t = 0; t < T_LEN; ++t) {
    // r2-proven serial dropout poll. Satisfied lanes drop out (exec-masked);
    // wave lockstep re-converges all 64 lanes before the reduce.
    const u32 tag = (u32)(t & 3);
    const u32* p  = ppoll0 + (t & 1) * SLOT_U32;
    u32x4 hA, hB, hC, hD;
    for (;;) {
      poll_group(p, hA, hB, hC, hD);
      const u32 m = (hA.x ^ tag) | (hA.y ^ tag) | (hA.z ^ tag) | (hA.w ^ tag)
                  | (hB.x ^ tag) | (hB.y ^ tag) | (hB.z ^ tag) | (hB.w ^ tag)
                  | (hC.x ^ tag) | (hC.y ^ tag) | (hC.z ^ tag) | (hC.w ^ tag)
                  | (hD.x ^ tag) | (hD.y ^ tag) | (hD.z ^ tag) | (hD.w ^ tag);
      if ((m & 3u) == 0u) break;
      if (--dead == 0) { timeout = true; break; }
    }
    if (__any(timeout)) {
      if (lane == 0) coh_store1(ws + FLAG_OFF, 1u);  // fail fast, release fillers
      return;
    }

    // Issue bx(t+2) now; ~2 full step periods to cover HBM latency.
    const int tn2 = (t + 2 < T_LEN) ? t + 2 : t;
    const float bx_n2 = out[(size_t)tn2 * H_DIM + row];

    // Partial dots straight from poll registers (tag bits left in mantissa,
    // rel err <= 2^-22 -- same as proven version).
    const f32x4 fh[4] = { __builtin_bit_cast(f32x4, hA),
                          __builtin_bit_cast(f32x4, hB),
                          __builtin_bit_cast(f32x4, hC),
                          __builtin_bit_cast(f32x4, hD) };
    float ac0 = 0.f, ac1 = 0.f, ac2 = 0.f, ac3 = 0.f;
    if constexpr (FAST) {
#pragma unroll
      for (int k4 = 0; k4 < 4; ++k4) {
        const f32x4 h4 = fh[k4];
        const f32x4 a0 = *(const f32x4*)(ab + (0 * 4 + k4) * 256);
        const f32x4 a1 = *(const f32x4*)(ab + (1 * 4 + k4) * 256);
        const f32x4 a2 = *(const f32x4*)(ab + (2 * 4 + k4) * 256);
        const f32x4 a3 = *(const f32x4*)(ab + (3 * 4 + k4) * 256);
#pragma unroll
        for (int q = 0; q < 4; ++q) {
          ac0 = fmaf(a0[q], h4[q], ac0);
          ac1 = fmaf(a1[q], h4[q], ac1);
          ac2 = fmaf(a2[q], h4[q], ac2);
          ac3 = fmaf(a3[q], h4[q], ac3);
        }
      }
    } else {
#pragma unroll
      for (int k4 = 0; k4 < 4; ++k4) {
        const f32x4 h4 = fh[k4];
#pragma unroll
        for (int q = 0; q < 4; ++q) {
          ac0 = fmaf(a[0][k4 * 4 + q], h4[q], ac0);
          ac1 = fmaf(a[1][k4 * 4 + q], h4[q], ac1);
          ac2 = fmaf(a[2][k4 * 4 + q], h4[q], ac2);
          ac3 = fmaf(a[3][k4 * 4 + q], h4[q], ac3);
        }
      }
    }

    // Transposed reduce [r6-r8 HW-proven]: lane l ends holding the full
    // 64-lane sum of ac_{l&3} == its own row's dot product.
    const float lo01 = (lane & 1) ? ac1 : ac0;
    const float ot01 = (lane & 1) ? ac0 : ac1;
    const float lo23 = (lane & 1) ? ac3 : ac2;
    const float ot23 = (lane & 1) ? ac2 : ac3;
    const float p01  = lo01 + dpp_xor1(ot01);
    const float p23  = lo23 + dpp_xor1(ot23);
    const float keep = (lane & 2) ? p23 : p01;
    const float give = (lane & 2) ? p01 : p23;
    float x = keep + dpp_xor2(give);
    x += __shfl_xor(x, 4, 64);
    x += __shfl_xor(x, 8, 64);
    x += __shfl_xor(x, 16, 64);
    x += __shfl_xor(x, 32, 64);

    const float v = fast_tanh(x + bx_val);
    bx_val = bx_n1;
    bx_n1  = bx_n2;

    const u32 nt = (u32)((t + 1) & 3);
    if (lane < 4 * NREP) {
      // lanes 0..31: publish to replica lane>>2, row-class lane&3.
      coh_store1(pub + (size_t)((t + 1) & 1) * SLOT_U32,
                 (__float_as_uint(v) & ~3u) | nt);
    } else if (lane < 4 * NREP + 4) {
      // lanes 32..35: clean output write (bx already consumed this step).
      out[(size_t)t * H_DIM + row] = v;
    }
  }

  if (gw == 0 && lane == 0) coh_store1(ws + FLAG_OFF, 1u);  // release fillers
}

// ---------------------------------------------------------------------------
extern "C" void kernel_launch(void* const* d_in, const int* in_sizes, int n_in,
                              void* d_out, int out_size, void* d_ws, size_t ws_size,
                              hipStream_t stream) {
  const float* x    = (const float*)d_in[0];  // (T, X)
  const float* h0   = (const float*)d_in[1];  // (H,)
  const float* Araw = (const float*)d_in[2];  // (H, H)
  const float* B    = (const float*)d_in[3];  // (H, X)
  const float* c    = (const float*)d_in[4];  // (H,)
  float* out = (float*)d_out;                 // (T, H)
  u32* ws    = (u32*)d_ws;                    // hbuf + flags [+ Atrans]

  const bool fast = ws_size >= WS_NEED;       // constant across graph replays

  hinit<<<1, 256, 0, stream>>>(h0, ws);
  if (fast) aprep<<<256, 256, 0, stream>>>(Araw, (float*)(ws + ATR_OFF_U32));
  dim3 g(T_LEN / 64, H_DIM / 64);
  gemm_bx<<<g, 256, 0, stream>>>(x, B, c, out);
  if (fast) rnn_scan<true ><<<256, 256, 0, stream>>>(Araw, out, ws);
  else      rnn_scan<false><<<256, 256, 0, stream>>>(Araw, out, ws);
}